// Round 2
// baseline (40714.276 us; speedup 1.0000x reference)
//
#include <hip/hip_runtime.h>

#define NSTEP 512     // T*H*W sequence length
#define EDIM  512     // input feature dim
#define REC   2048    // recurrent dim
#define NB    64      // batch rows
#define KSEL  819     // int(2048*0.4)
#define KC    8       // K-split chunks (grid kc dim)
#define NC    32      // col chunks of 64 (grid nc dim)
#define ZCH   256     // K per chunk for z (r @ Wr), KC*ZCH = 2048
#define YCH   64      // K per chunk for y (x @ Wi), KC*YCH = 512
#define KB    64      // K per LDS staging round

// ---------------------------------------------------------------------------
// Two-level monotonic grid barrier. 256 blocks = 16 groups x 16.
// bar[g*16] = per-group arrival counters (64B apart); bar[512] = root.
// Monotonic counters -> no reset races. __threadfence gives agent-scope
// release/acquire (L2 writeback/invalidate on gfx950) for cross-XCD data.
// ---------------------------------------------------------------------------
__device__ __forceinline__ void grid_barrier(unsigned* bar, int bid, unsigned gen)
{
    __syncthreads();                       // all block stores drained (vmcnt)
    if (threadIdx.x == 0) {
        __threadfence();                   // release: flush to coherence point
        const int g = bid >> 4;
        unsigned v = __hip_atomic_fetch_add(&bar[g * 16], 1u,
                        __ATOMIC_RELAXED, __HIP_MEMORY_SCOPE_AGENT);
        if (v + 1u == gen * 16u)           // last arriver of this group
            __hip_atomic_fetch_add(&bar[512], 1u,
                        __ATOMIC_RELAXED, __HIP_MEMORY_SCOPE_AGENT);
        while (__hip_atomic_load(&bar[512], __ATOMIC_RELAXED,
                        __HIP_MEMORY_SCOPE_AGENT) < gen * 16u)
            __builtin_amdgcn_s_sleep(1);
        __threadfence();                   // acquire: invalidate stale caches
    }
    __syncthreads();
}

// ---------------------------------------------------------------------------
// One staging+compute round: C[64 rows][64 cols] += A[64][KB] * B[KB][64]
// A row lm at Arow_base + lm*a_stride + a_off.  B rows bk0.. of [*, REC].
// Lane-layout: m = tid&63 (row), wloc = (tid>>6)*16 (col base, 16 cols/thread).
// A-read: ds_read_b32 divergent (2-way bank alias, free).
// B-read: wave-uniform address -> LDS broadcast (16B/instr).
// ---------------------------------------------------------------------------
__device__ __forceinline__ void gemm_round(
    const float* __restrict__ Arow_base, long long a_stride, int a_off,
    const float* __restrict__ B, int bk0, int n0,
    float* aS, float* bS, float acc[16], int m, int wloc)
{
    const int tid = threadIdx.x;
    {   // stage A: KB x 64 transposed (aS[k][m]), coalesced float4 loads
        const int lm = tid & 63;
        const int kq = (tid >> 6) * 16;
        const float* ar = Arow_base + (long long)lm * a_stride + a_off + kq;
#pragma unroll
        for (int i = 0; i < 16; i += 4) {
            float4 v = *(const float4*)(ar + i);
            aS[(kq + i    ) * 64 + lm] = v.x;
            aS[(kq + i + 1) * 64 + lm] = v.y;
            aS[(kq + i + 2) * 64 + lm] = v.z;
            aS[(kq + i + 3) * 64 + lm] = v.w;
        }
    }
    {   // stage B: KB x 64, row-major, coalesced float4 -> ds_write_b128
        const int c4  = (tid & 15) * 4;
        const int kk0 = tid >> 4;
#pragma unroll
        for (int p = 0; p < 4; ++p) {
            const int kk = kk0 + p * 16;
            float4 v = *(const float4*)(B + (long long)(bk0 + kk) * REC + n0 + c4);
            *(float4*)&bS[kk * 64 + c4] = v;
        }
    }
    __syncthreads();
#pragma unroll 16
    for (int kk = 0; kk < KB; ++kk) {
        const float a = aS[kk * 64 + m];
        const float4 b0 = *(const float4*)&bS[kk * 64 + wloc];
        const float4 b1 = *(const float4*)&bS[kk * 64 + wloc + 4];
        const float4 b2 = *(const float4*)&bS[kk * 64 + wloc + 8];
        const float4 b3 = *(const float4*)&bS[kk * 64 + wloc + 12];
        acc[0]  += a * b0.x;  acc[1]  += a * b0.y;  acc[2]  += a * b0.z;  acc[3]  += a * b0.w;
        acc[4]  += a * b1.x;  acc[5]  += a * b1.y;  acc[6]  += a * b1.z;  acc[7]  += a * b1.w;
        acc[8]  += a * b2.x;  acc[9]  += a * b2.y;  acc[10] += a * b2.z;  acc[11] += a * b2.w;
        acc[12] += a * b3.x;  acc[13] += a * b3.y;  acc[14] += a * b3.z;  acc[15] += a * b3.w;
    }
    __syncthreads();
}

// ---------------------------------------------------------------------------
// Persistent kernel: 256 blocks x 256 threads, whole 512-step recurrence.
// Block (nc,kc): GEMM partial for cols [nc*64,+64), K-chunk kc.
// Blocks 0..63 additionally run the per-row update phase.
// ---------------------------------------------------------------------------
__global__ __launch_bounds__(256)
void rnn_persistent(const float* __restrict__ x, const float* __restrict__ Wi,
                    const float* __restrict__ Wr, float* __restrict__ r,
                    float* __restrict__ zpart, float* __restrict__ ypart,
                    unsigned* __restrict__ bar)
{
    __shared__ __align__(16) char smem[32768];
    float* aS = (float*)smem;                       // [KB][64] = 16 KB
    float* bS = (float*)(smem + 16384);             // [KB][64] = 16 KB
    // update-phase views (phases separated by grid barriers)
    unsigned*      kS   = (unsigned*)smem;          // [2048] keys, 8 KB
    unsigned char* selS = (unsigned char*)(smem + 8192);   // [2048]
    unsigned*      hist = (unsigned*)(smem + 10240);       // [256]
    unsigned*      scn  = (unsigned*)(smem + 11264);       // [256]
    __shared__ unsigned s_byte, s_newrem;
    __shared__ float red[4];
    __shared__ float s_norm;

    const int bid = blockIdx.x;
    const int tid = threadIdx.x;
    const int nc  = bid & 31;
    const int kc  = bid >> 5;
    const int n0  = nc * 64;
    const int m   = tid & 63;
    const int wloc = (tid >> 6) * 16;
    unsigned gen = 0;

    // r0 = 0 (d_out is poisoned before every replay)
    for (int i = tid; i < 512; i += 256)
        r[(long long)bid * 512 + i] = 0.f;
    ++gen; grid_barrier(bar, bid, gen);

    for (int t = 0; t < NSTEP; ++t) {
        float acc[16];
#pragma unroll
        for (int i = 0; i < 16; ++i) acc[i] = 0.f;
        // ---- z partial: r @ Wr over K-chunk [kc*256, +256) ----
        for (int kb = 0; kb < ZCH; kb += KB)
            gemm_round(r, (long long)REC, kc * ZCH + kb,
                       Wr, kc * ZCH + kb, n0, aS, bS, acc, m, wloc);
        {
            float* zp = zpart + ((long long)(kc * 64 + m)) * REC + n0 + wloc;
            *(float4*)&zp[0]  = make_float4(acc[0],  acc[1],  acc[2],  acc[3]);
            *(float4*)&zp[4]  = make_float4(acc[4],  acc[5],  acc[6],  acc[7]);
            *(float4*)&zp[8]  = make_float4(acc[8],  acc[9],  acc[10], acc[11]);
            *(float4*)&zp[12] = make_float4(acc[12], acc[13], acc[14], acc[15]);
        }
#pragma unroll
        for (int i = 0; i < 16; ++i) acc[i] = 0.f;
        // ---- y partial: x_t @ Wi over K-chunk [kc*64, +64) ----
        gemm_round(x, (long long)NSTEP * EDIM, t * EDIM + kc * YCH,
                   Wi, kc * YCH, n0, aS, bS, acc, m, wloc);
        {
            float* yp = ypart + ((long long)(kc * 64 + m)) * REC + n0 + wloc;
            *(float4*)&yp[0]  = make_float4(acc[0],  acc[1],  acc[2],  acc[3]);
            *(float4*)&yp[4]  = make_float4(acc[4],  acc[5],  acc[6],  acc[7]);
            *(float4*)&yp[8]  = make_float4(acc[8],  acc[9],  acc[10], acc[11]);
            *(float4*)&yp[12] = make_float4(acc[12], acc[13], acc[14], acc[15]);
        }
        ++gen; grid_barrier(bar, bid, gen);   // partials ready

        // ---- update phase: blocks 0..63, one batch row each ----
        if (bid < NB) {
            const int b = bid;
            float zr[8], yv[8], rn[8];
#pragma unroll
            for (int s = 0; s < 8; ++s) {
                const int j = tid + 256 * s;
                float a = 0.f, yy = 0.f;
#pragma unroll
                for (int k2 = 0; k2 < KC; ++k2) {
                    a  += zpart[((long long)(k2 * 64 + b)) * REC + j];
                    yy += ypart[((long long)(k2 * 64 + b)) * REC + j];
                }
                zr[s] = a; yv[s] = yy;
                const unsigned u = __float_as_uint(a);
                kS[j] = (u & 0x80000000u) ? ~u : (u | 0x80000000u);  // desc order
            }
            __syncthreads();
            // MSD radix select: key T of the KSEL-th largest
            unsigned prefix = 0, remaining = KSEL;
            for (int byte = 3; byte >= 0; --byte) {
                hist[tid] = 0u; __syncthreads();
                const int shift = byte * 8;
                const unsigned pmask = (byte == 3) ? 0u : (0xFFFFFFFFu << (shift + 8));
#pragma unroll
                for (int s = 0; s < 8; ++s) {
                    const unsigned key = kS[tid + 256 * s];
                    if ((key & pmask) == prefix)
                        atomicAdd(&hist[(key >> shift) & 255u], 1u);
                }
                __syncthreads();
                if (tid < 64) {   // wave 0: suffix-sum over 256 bins
                    const unsigned h0 = hist[tid * 4 + 0];
                    const unsigned h1 = hist[tid * 4 + 1];
                    const unsigned h2 = hist[tid * 4 + 2];
                    const unsigned h3 = hist[tid * 4 + 3];
                    const unsigned tot = h0 + h1 + h2 + h3;
                    unsigned suf = tot;
#pragma unroll
                    for (int st = 1; st < 64; st <<= 1) {
                        unsigned o = __shfl_down(suf, (unsigned)st);
                        if (tid + st >= 64) o = 0u;
                        suf += o;
                    }
                    unsigned S[5];
                    S[0] = suf; S[1] = suf - h0; S[2] = suf - h0 - h1;
                    S[3] = suf - h0 - h1 - h2; S[4] = suf - tot;
#pragma unroll
                    for (int q = 0; q < 4; ++q) {
                        if (S[q] >= remaining && S[q + 1] < remaining) {
                            s_byte = (unsigned)(tid * 4 + q);
                            s_newrem = remaining - S[q + 1];
                        }
                    }
                }
                __syncthreads();
                prefix |= (s_byte << shift);
                remaining = s_newrem;
                __syncthreads();
            }
            const unsigned T = prefix;
            const unsigned need = remaining;
            const unsigned cnteq = hist[T & 255u];
            if (need == cnteq) {
#pragma unroll
                for (int s = 0; s < 8; ++s) {
                    const int j = tid + 256 * s;
                    selS[j] = (kS[j] >= T) ? 1 : 0;
                }
            } else {
                // tie at threshold: keep lowest indices (lax.top_k order) —
                // parallel: eq flags -> blocked prefix ranks
#pragma unroll
                for (int s = 0; s < 8; ++s) {
                    const int j = tid + 256 * s;
                    selS[j] = (kS[j] == T) ? 1 : 0;
                }
                __syncthreads();
                int c = 0;
                unsigned char eqv[8];
#pragma unroll
                for (int i = 0; i < 8; ++i) { eqv[i] = selS[tid * 8 + i]; c += eqv[i]; }
                scn[tid] = (unsigned)c; __syncthreads();
                for (int st = 1; st < 256; st <<= 1) {
                    unsigned v2 = (tid >= st) ? scn[tid - st] : 0u;
                    __syncthreads();
                    scn[tid] += v2;
                    __syncthreads();
                }
                unsigned p = scn[tid] - (unsigned)c;   // eq-rank before my chunk
#pragma unroll
                for (int i = 0; i < 8; ++i) {
                    const int j = tid * 8 + i;
                    unsigned char sel;
                    if (eqv[i]) { sel = (p < need) ? 1 : 0; ++p; }
                    else        { sel = (kS[j] > T) ? 1 : 0; }
                    selS[j] = sel;
                }
            }
            __syncthreads();
            // r_new = tanh(y + masked z), row-normalize
            float sumsq = 0.f;
#pragma unroll
            for (int s = 0; s < 8; ++s) {
                const int j = tid + 256 * s;
                const float v = yv[s] + (selS[j] ? zr[s] : 0.f);
                const float th = tanhf(v);
                rn[s] = th; sumsq += th * th;
            }
#pragma unroll
            for (int off = 32; off > 0; off >>= 1)
                sumsq += __shfl_down(sumsq, (unsigned)off);
            const int lane = tid & 63, wvi = tid >> 6;
            if (lane == 0) red[wvi] = sumsq;
            __syncthreads();
            if (tid == 0) s_norm = sqrtf(red[0] + red[1] + red[2] + red[3]) + 1e-6f;
            __syncthreads();
            const float inv = 1.0f / s_norm;
#pragma unroll
            for (int s = 0; s < 8; ++s)
                r[(long long)b * REC + tid + 256 * s] = rn[s] * inv;
        }
        ++gen; grid_barrier(bar, bid, gen);   // r ready for next step
    }
}

// ---------------------------------------------------------------------------
extern "C" void kernel_launch(void* const* d_in, const int* in_sizes, int n_in,
                              void* d_out, int out_size, void* d_ws, size_t ws_size,
                              hipStream_t stream)
{
    const float* x   = (const float*)d_in[0];   // [64][512][512]
    const float* Win = (const float*)d_in[1];   // [512][2048]
    const float* Wr  = (const float*)d_in[2];   // [2048][2048]
    float* r = (float*)d_out;                   // [64][2048] recurrent state

    char* ws = (char*)d_ws;
    unsigned* bar = (unsigned*)ws;                               // 4 KB
    float* zpart = (float*)(ws + 4096);                          // 4 MB
    float* ypart = (float*)(ws + 4096 + (size_t)KC * NB * REC * 4); // 4 MB

    hipMemsetAsync(bar, 0, 4096, stream);   // zero barrier counters
    rnn_persistent<<<256, 256, 0, stream>>>(x, Win, Wr, r, zpart, ypart, bar);
}

// Round 3
// 18428.029 us; speedup vs baseline: 2.2094x; 2.2094x over previous
//
#include <hip/hip_runtime.h>

#define NSTEP 512     // T*H*W sequence length
#define EDIM  512     // input feature dim
#define REC   2048    // recurrent dim
#define NB    64      // batch rows
#define KSEL  819     // int(2048*0.4)
#define NC    16      // col chunks of 128
#define KC    16      // K chunks
#define ZCH   128     // K per chunk, z (KC*ZCH = 2048)
#define YCH   32      // K per chunk, y (KC*YCH = 512)
#define COLS  128     // cols per block

// ---- coherent (agent-scope, sc1) load/store helpers: write-through /
// ---- L2-bypass, so cross-XCD data needs NO cache-flush fences ----
__device__ __forceinline__ void cstore8(float* p, float a, float b) {
    float2 v = make_float2(a, b);
    unsigned long long u; __builtin_memcpy(&u, &v, 8);
    __hip_atomic_store((unsigned long long*)p, u, __ATOMIC_RELAXED, __HIP_MEMORY_SCOPE_AGENT);
}
__device__ __forceinline__ float2 cload8(const float* p) {
    unsigned long long u = __hip_atomic_load((unsigned long long*)p, __ATOMIC_RELAXED, __HIP_MEMORY_SCOPE_AGENT);
    float2 v; __builtin_memcpy(&v, &u, 8);
    return v;
}
__device__ __forceinline__ void cstore4(float* p, float a) {
    __hip_atomic_store((unsigned*)p, __float_as_uint(a), __ATOMIC_RELAXED, __HIP_MEMORY_SCOPE_AGENT);
}

// ---- two-level grid barrier, NO threadfence (all shared data is sc1) ----
// __syncthreads drains each wave's vmcnt before s_barrier, so all sc1
// stores are globally visible before thread 0 arrives.
__device__ __forceinline__ void gbar(unsigned* bar, int bid, unsigned gen)
{
    __syncthreads();
    if (threadIdx.x == 0) {
        const int g = bid >> 4;                  // 16 groups x 16 blocks
        unsigned v = __hip_atomic_fetch_add(&bar[g * 32], 1u,
                        __ATOMIC_RELAXED, __HIP_MEMORY_SCOPE_AGENT);
        if (v + 1u == gen * 16u)
            __hip_atomic_fetch_add(&bar[1024], 1u,
                        __ATOMIC_RELAXED, __HIP_MEMORY_SCOPE_AGENT);
        while (__hip_atomic_load(&bar[1024], __ATOMIC_RELAXED,
                        __HIP_MEMORY_SCOPE_AGENT) < gen * 16u)
            __builtin_amdgcn_s_sleep(2);
        __asm__ volatile("" ::: "memory");       // no hoisting loads above poll
    }
    __syncthreads();
}

// ---------------------------------------------------------------------------
// Persistent kernel: 256 blocks x 512 threads.
// Block (nc,kc): cols [nc*128,+128), K-chunk kc. Wr/Wi tiles live in LDS.
// Blocks 0..63 run the per-row update phase.
// LDS (120 KB dynamic): WrS 64K | WiS 16K | aS 32K (zA tile / update scratch)
//                       | ayS 8K
// ---------------------------------------------------------------------------
__global__ __launch_bounds__(512, 1)
void rnn_persistent(const float* __restrict__ x, const float* __restrict__ Wi,
                    const float* __restrict__ Wr, float* __restrict__ out,
                    float* __restrict__ rT, float* __restrict__ zpart,
                    float* __restrict__ ypart, unsigned* __restrict__ bar)
{
    extern __shared__ __align__(16) char smem[];
    float* WrS = (float*)smem;                    // [128][128] 64 KB
    float* WiS = (float*)(smem + 65536);          // [32][128]  16 KB
    float* aS  = (float*)(smem + 81920);          // [128][64]  32 KB
    float* ayS = (float*)(smem + 114688);         // [32][64]    8 KB
    // update-phase views of aS region
    unsigned*      kS   = (unsigned*)aS;                  // [2048] 8 KB
    unsigned char* selS = (unsigned char*)(smem + 81920 + 8192);   // 2 KB
    unsigned*      hist = (unsigned*)(smem + 81920 + 10240);       // 1 KB
    unsigned*      scn  = (unsigned*)(smem + 81920 + 11264);       // 2 KB
    __shared__ unsigned s_byte, s_newrem;
    __shared__ float red[8];
    __shared__ float s_norm;

    const int bid = blockIdx.x;
    const int tid = threadIdx.x;
    const int nc  = bid & 15;
    const int kc  = bid >> 4;
    const int n0  = nc * COLS;
    const int tr4 = (tid >> 5) * 4;   // row base (0..60)
    const int tc4 = (tid & 31) * 4;   // col base (0..124)
    unsigned gen = 0;

    // ---- one-time staging: Wr tile [kc*128,+128) x [n0,+128) ----
    {
        const int r = tid >> 2, q = (tid & 3) * 32;
        const float* src = Wr + (long long)(kc * ZCH + r) * REC + n0 + q;
#pragma unroll
        for (int i = 0; i < 32; i += 4)
            *(float4*)&WrS[r * COLS + q + i] = *(const float4*)(src + i);
    }
    {   // Wi tile [kc*32,+32) x [n0,+128)
        const int r = tid >> 4, q = (tid & 15) * 8;
        const float* src = Wi + (long long)(kc * YCH + r) * REC + n0 + q;
        *(float4*)&WiS[r * COLS + q]     = *(const float4*)(src);
        *(float4*)&WiS[r * COLS + q + 4] = *(const float4*)(src + 4);
    }
    // ---- init rT = 0 (256*512 threads == 131072 == 64*2048) ----
    cstore4(rT + (long long)bid * 512 + tid, 0.f);
    ++gen; gbar(bar, bid, gen);

    for (int t = 0; t < NSTEP; ++t) {
        // ---- stage z A-tile: rT[kc*128 : +128][0:64] (contiguous, sc1) ----
        {
            const float* src = rT + kc * ZCH * 64;
#pragma unroll
            for (int u = 0; u < 8; ++u) {
                const int idx = (tid + 512 * u) * 2;
                float2 v = cload8(src + idx);
                *(float2*)&aS[idx] = v;
            }
        }
        // ---- stage y A-tile (transpose x): ayS[e][b] ----
        {
            const int b = tid & 63, q = (tid >> 6) * 4;
            const float4 v = *(const float4*)(x + ((long long)b * NSTEP + t) * EDIM + kc * YCH + q);
            ayS[(q    ) * 64 + b] = v.x;
            ayS[(q + 1) * 64 + b] = v.y;
            ayS[(q + 2) * 64 + b] = v.z;
            ayS[(q + 3) * 64 + b] = v.w;
        }
        __syncthreads();

        // ---- z partial: 4x4 register block, 2 LDS instr per 16 FMA ----
        float4 a0 = {0,0,0,0}, a1 = {0,0,0,0}, a2 = {0,0,0,0}, a3 = {0,0,0,0};
#pragma unroll 8
        for (int kk = 0; kk < ZCH; ++kk) {
            const float4 af = *(const float4*)&aS[kk * 64 + tr4];
            const float4 bf = *(const float4*)&WrS[kk * COLS + tc4];
            a0.x += af.x * bf.x; a0.y += af.x * bf.y; a0.z += af.x * bf.z; a0.w += af.x * bf.w;
            a1.x += af.y * bf.x; a1.y += af.y * bf.y; a1.z += af.y * bf.z; a1.w += af.y * bf.w;
            a2.x += af.z * bf.x; a2.y += af.z * bf.y; a2.z += af.z * bf.z; a2.w += af.z * bf.w;
            a3.x += af.w * bf.x; a3.y += af.w * bf.y; a3.z += af.w * bf.z; a3.w += af.w * bf.w;
        }
        {
            float* zp = zpart + ((long long)(kc * 64) + tr4) * REC + n0 + tc4;
            cstore8(zp,            a0.x, a0.y); cstore8(zp + 2,            a0.z, a0.w);
            cstore8(zp + REC,      a1.x, a1.y); cstore8(zp + REC + 2,      a1.z, a1.w);
            cstore8(zp + 2 * REC,  a2.x, a2.y); cstore8(zp + 2 * REC + 2,  a2.z, a2.w);
            cstore8(zp + 3 * REC,  a3.x, a3.y); cstore8(zp + 3 * REC + 2,  a3.z, a3.w);
        }
        // ---- y partial ----
        a0 = make_float4(0,0,0,0); a1 = make_float4(0,0,0,0);
        a2 = make_float4(0,0,0,0); a3 = make_float4(0,0,0,0);
#pragma unroll 8
        for (int kk = 0; kk < YCH; ++kk) {
            const float4 af = *(const float4*)&ayS[kk * 64 + tr4];
            const float4 bf = *(const float4*)&WiS[kk * COLS + tc4];
            a0.x += af.x * bf.x; a0.y += af.x * bf.y; a0.z += af.x * bf.z; a0.w += af.x * bf.w;
            a1.x += af.y * bf.x; a1.y += af.y * bf.y; a1.z += af.y * bf.z; a1.w += af.y * bf.w;
            a2.x += af.z * bf.x; a2.y += af.z * bf.y; a2.z += af.z * bf.z; a2.w += af.z * bf.w;
            a3.x += af.w * bf.x; a3.y += af.w * bf.y; a3.z += af.w * bf.z; a3.w += af.w * bf.w;
        }
        {
            float* yp = ypart + ((long long)(kc * 64) + tr4) * REC + n0 + tc4;
            cstore8(yp,            a0.x, a0.y); cstore8(yp + 2,            a0.z, a0.w);
            cstore8(yp + REC,      a1.x, a1.y); cstore8(yp + REC + 2,      a1.z, a1.w);
            cstore8(yp + 2 * REC,  a2.x, a2.y); cstore8(yp + 2 * REC + 2,  a2.z, a2.w);
            cstore8(yp + 3 * REC,  a3.x, a3.y); cstore8(yp + 3 * REC + 2,  a3.z, a3.w);
        }
        ++gen; gbar(bar, bid, gen);   // partials globally visible

        // ================= update phase: blocks 0..63 =================
        if (bid < NB) {
            const int b = bid;
            const int j0 = tid * 4;
            float zs[4] = {0,0,0,0}, ys[4] = {0,0,0,0};
#pragma unroll
            for (int k2 = 0; k2 < KC; ++k2) {
                const long long base = ((long long)(k2 * 64) + b) * REC + j0;
                float2 u0 = cload8(zpart + base);
                float2 u1 = cload8(zpart + base + 2);
                zs[0] += u0.x; zs[1] += u0.y; zs[2] += u1.x; zs[3] += u1.y;
                float2 w0 = cload8(ypart + base);
                float2 w1 = cload8(ypart + base + 2);
                ys[0] += w0.x; ys[1] += w0.y; ys[2] += w1.x; ys[3] += w1.y;
            }
            {
                uint4 kv;
                unsigned u;
                u = __float_as_uint(zs[0]); kv.x = (u & 0x80000000u) ? ~u : (u | 0x80000000u);
                u = __float_as_uint(zs[1]); kv.y = (u & 0x80000000u) ? ~u : (u | 0x80000000u);
                u = __float_as_uint(zs[2]); kv.z = (u & 0x80000000u) ? ~u : (u | 0x80000000u);
                u = __float_as_uint(zs[3]); kv.w = (u & 0x80000000u) ? ~u : (u | 0x80000000u);
                *(uint4*)&kS[j0] = kv;
            }
            __syncthreads();
            // MSD radix select: key T of the KSEL-th largest
            unsigned prefix = 0, remaining = KSEL;
            for (int byte = 3; byte >= 0; --byte) {
                if (tid < 256) hist[tid] = 0u;
                __syncthreads();
                const int shift = byte * 8;
                const unsigned pmask = (byte == 3) ? 0u : (0xFFFFFFFFu << (shift + 8));
#pragma unroll
                for (int s = 0; s < 4; ++s) {
                    const unsigned key = kS[j0 + s];
                    if ((key & pmask) == prefix)
                        atomicAdd(&hist[(key >> shift) & 255u], 1u);
                }
                __syncthreads();
                if (tid < 64) {   // wave 0: suffix-sum over 256 bins
                    const unsigned h0 = hist[tid * 4 + 0];
                    const unsigned h1 = hist[tid * 4 + 1];
                    const unsigned h2 = hist[tid * 4 + 2];
                    const unsigned h3 = hist[tid * 4 + 3];
                    const unsigned tot = h0 + h1 + h2 + h3;
                    unsigned suf = tot;
#pragma unroll
                    for (int st = 1; st < 64; st <<= 1) {
                        unsigned o = __shfl_down(suf, (unsigned)st);
                        if (tid + st >= 64) o = 0u;
                        suf += o;
                    }
                    unsigned S[5];
                    S[0] = suf; S[1] = suf - h0; S[2] = suf - h0 - h1;
                    S[3] = suf - h0 - h1 - h2; S[4] = suf - tot;
#pragma unroll
                    for (int q = 0; q < 4; ++q) {
                        if (S[q] >= remaining && S[q + 1] < remaining) {
                            s_byte = (unsigned)(tid * 4 + q);
                            s_newrem = remaining - S[q + 1];
                        }
                    }
                }
                __syncthreads();
                prefix |= (s_byte << shift);
                remaining = s_newrem;
                __syncthreads();
            }
            const unsigned T = prefix;
            const unsigned need = remaining;
            const unsigned cnteq = hist[T & 255u];
            if (need == cnteq) {
#pragma unroll
                for (int s = 0; s < 4; ++s)
                    selS[j0 + s] = (kS[j0 + s] >= T) ? 1 : 0;
                __syncthreads();
            } else {
                // tie at threshold: keep lowest indices (lax.top_k order)
                int c = 0; unsigned char eqv[4];
#pragma unroll
                for (int s = 0; s < 4; ++s) { eqv[s] = (kS[j0 + s] == T) ? 1 : 0; c += eqv[s]; }
                scn[tid] = (unsigned)c; __syncthreads();
                for (int st = 1; st < 512; st <<= 1) {
                    unsigned v2 = (tid >= st) ? scn[tid - st] : 0u;
                    __syncthreads();
                    scn[tid] += v2;
                    __syncthreads();
                }
                unsigned p = scn[tid] - (unsigned)c;
#pragma unroll
                for (int s = 0; s < 4; ++s) {
                    unsigned char sel;
                    if (eqv[s]) { sel = (p < need) ? 1 : 0; ++p; }
                    else        { sel = (kS[j0 + s] > T) ? 1 : 0; }
                    selS[j0 + s] = sel;
                }
                __syncthreads();
            }
            // r_new = tanh(y + masked z), row-normalize
            float rn[4]; float ss = 0.f;
#pragma unroll
            for (int s = 0; s < 4; ++s) {
                const float v = ys[s] + (selS[j0 + s] ? zs[s] : 0.f);
                const float th = tanhf(v);
                rn[s] = th; ss += th * th;
            }
#pragma unroll
            for (int off = 32; off > 0; off >>= 1)
                ss += __shfl_down(ss, (unsigned)off);
            const int lane = tid & 63, wvi = tid >> 6;
            if (lane == 0) red[wvi] = ss;
            __syncthreads();
            if (tid == 0) {
                float a = 0.f;
#pragma unroll
                for (int i = 0; i < 8; ++i) a += red[i];
                s_norm = sqrtf(a) + 1e-6f;
            }
            __syncthreads();
            const float inv = 1.0f / s_norm;
#pragma unroll
            for (int s = 0; s < 4; ++s) {
                const float v = rn[s] * inv;
                cstore4(rT + (long long)(j0 + s) * 64 + b, v);   // transposed state
                rn[s] = v;
            }
            if (t == NSTEP - 1) {
                float4 o = make_float4(rn[0], rn[1], rn[2], rn[3]);
                *(float4*)&out[(long long)b * REC + j0] = o;
            }
        }
        ++gen; gbar(bar, bid, gen);   // r ready for next step
    }
}

// ---------------------------------------------------------------------------
extern "C" void kernel_launch(void* const* d_in, const int* in_sizes, int n_in,
                              void* d_out, int out_size, void* d_ws, size_t ws_size,
                              hipStream_t stream)
{
    const float* x   = (const float*)d_in[0];   // [64][512][512]
    const float* Win = (const float*)d_in[1];   // [512][2048]
    const float* Wr  = (const float*)d_in[2];   // [2048][2048]
    float* out = (float*)d_out;                 // [64][2048]

    char* ws = (char*)d_ws;
    unsigned* bar = (unsigned*)ws;                        // 8 KB
    float* rT    = (float*)(ws + 8192);                   // 512 KB (transposed r)
    float* zpart = (float*)(ws + 8192 + 524288);          // 8 MB
    float* ypart = (float*)(ws + 8192 + 524288 + 8388608);// 8 MB

    static int smem_set = 0;
    if (!smem_set) {
        hipFuncSetAttribute((const void*)rnn_persistent,
                            hipFuncAttributeMaxDynamicSharedMemorySize, 122880);
        smem_set = 1;
    }
    hipMemsetAsync(bar, 0, 8192, stream);
    rnn_persistent<<<256, 512, 122880, stream>>>(x, Win, Wr, out, rT, zpart, ypart, bar);
}

// Round 4
// 12005.776 us; speedup vs baseline: 3.3912x; 1.5349x over previous
//
#include <hip/hip_runtime.h>

#define NSTEP 512
#define EDIM  512
#define REC   2048
#define NB    64
#define KSEL  819
#define NC    32      // col chunks of 64
#define KC    8       // K chunks of 256
#define ZCH   256     // K per block

typedef unsigned short u16;
typedef __bf16 bf16x8 __attribute__((ext_vector_type(8)));
typedef float  f32x4  __attribute__((ext_vector_type(4)));

static __device__ __forceinline__ f32x4 mfma16(bf16x8 a, bf16x8 b, f32x4 c) {
    return __builtin_amdgcn_mfma_f32_16x16x32_bf16(a, b, c, 0, 0, 0);
}

// fp32 -> 3 bf16 components (hi, mid, lo) ~26 mantissa bits
static __device__ __forceinline__ void split3(float v, u16& c0, u16& c1, u16& c2) {
    __bf16 b0 = (__bf16)v;
    float r1 = v - (float)b0;
    __bf16 b1 = (__bf16)r1;
    __bf16 b2 = (__bf16)(r1 - (float)b1);
    c0 = __builtin_bit_cast(u16, b0);
    c1 = __builtin_bit_cast(u16, b1);
    c2 = __builtin_bit_cast(u16, b2);
}

// ---- agent-scope (sc1) coherent access helpers: no cache-flush fences ----
static __device__ __forceinline__ void cstore4(float* p, float v) {
    __hip_atomic_store((unsigned*)p, __float_as_uint(v), __ATOMIC_RELAXED, __HIP_MEMORY_SCOPE_AGENT);
}
static __device__ __forceinline__ void cstore8u(void* p, unsigned long long v) {
    __hip_atomic_store((unsigned long long*)p, v, __ATOMIC_RELAXED, __HIP_MEMORY_SCOPE_AGENT);
}
static __device__ __forceinline__ unsigned long long cload8u(const void* p) {
    return __hip_atomic_load((const unsigned long long*)p, __ATOMIC_RELAXED, __HIP_MEMORY_SCOPE_AGENT);
}
static __device__ __forceinline__ float2 cload8f(const float* p) {
    unsigned long long u = cload8u(p);
    float2 v; __builtin_memcpy(&v, &u, 8);
    return v;
}

// ---- two-level grid barrier (proven round 3) ----
__device__ __forceinline__ void gbar(unsigned* bar, int bid, unsigned gen)
{
    __syncthreads();
    if (threadIdx.x == 0) {
        const int g = bid >> 4;                  // 16 groups x 16 blocks
        unsigned v = __hip_atomic_fetch_add(&bar[g * 32], 1u,
                        __ATOMIC_RELAXED, __HIP_MEMORY_SCOPE_AGENT);
        if (v + 1u == gen * 16u)
            __hip_atomic_fetch_add(&bar[1024], 1u,
                        __ATOMIC_RELAXED, __HIP_MEMORY_SCOPE_AGENT);
        while (__hip_atomic_load(&bar[1024], __ATOMIC_RELAXED,
                        __HIP_MEMORY_SCOPE_AGENT) < gen * 16u)
            __builtin_amdgcn_s_sleep(1);
        __asm__ volatile("" ::: "memory");
    }
    __syncthreads();
}

// ---------------------------------------------------------------------------
// Persistent kernel: 256 blocks x 512 threads.
// LDS map (129024 B dynamic):
//   WrSu: 3 x [64 n][264 k] bf16  @0       (101376 B)  pad 264 kills frag conflicts
//   aSu : 3 x [64 b][72 k]  bf16  @101376  (27648 B)   staging round K=64
//   update scratch aliases aSu; Y-precompute WiP/xP alias WrSu.
// ---------------------------------------------------------------------------
__global__ __launch_bounds__(512, 1)
void rnn_persistent(const float* __restrict__ x, const float* __restrict__ Wi,
                    const float* __restrict__ Wr, float* __restrict__ out,
                    u16* __restrict__ rTu, float* __restrict__ zpart,
                    u16* __restrict__ Ybf, unsigned* __restrict__ bar)
{
    extern __shared__ __align__(16) char smem[];
    u16* WrSu = (u16*)smem;                       // comp c: +c*16896 (u16 idx)
    u16* aSu  = (u16*)(smem + 101376);            // comp c: +c*4608
    // Y-precompute views
    float* WiP = (float*)smem;                    // [32][128] 16 KB
    float* xP  = (float*)(smem + 16384);          // [32][64]   8 KB
    // update views (alias aSu region)
    unsigned*      kS   = (unsigned*)(smem + 101376);        // [2048] 8 KB
    unsigned char* selS = (unsigned char*)(smem + 101376 + 8192);
    unsigned*      hist = (unsigned*)(smem + 101376 + 10240);
    unsigned*      scn  = (unsigned*)(smem + 101376 + 11264);
    __shared__ unsigned s_byte, s_newrem;
    __shared__ float red[8];
    __shared__ float s_norm;

    const int bid = blockIdx.x;
    const int tid = threadIdx.x;
    const int nc = bid & 31, kc = bid >> 5;
    const int n0 = nc * 64, kcbase = kc * ZCH;
    const int wid = tid >> 6, lane = tid & 63;
    const int q = lane >> 4, l16 = lane & 15;
    const int Moff = (wid & 3) * 16, Npair = wid >> 2;
    unsigned gen = 0;

    // ================= Y precompute: Y[t][b][j] = (x_t @ Wi) in bf16 ========
    {
        const int t0 = bid * 2;
        const int tr4 = (tid >> 5) * 4;      // b-row base
        const int tc4 = (tid & 31) * 4;      // col base (of 128)
        for (int nc2 = 0; nc2 < 16; ++nc2) {
            const int n0y = nc2 * 128;
            f32x4 acc[2][4];
#pragma unroll
            for (int h = 0; h < 2; ++h)
#pragma unroll
                for (int i = 0; i < 4; ++i) acc[h][i] = (f32x4){0,0,0,0};
            for (int kr = 0; kr < 16; ++kr) {
                const int k0y = kr * 32;
                __syncthreads();
                {   // stage WiP [32][128]
                    const int col4 = (tid & 31) * 4, row = tid >> 5;
                    *(float4*)&WiP[row * 128 + col4] =
                        *(const float4*)(Wi + (long long)(k0y + row) * REC + n0y + col4);
                    *(float4*)&WiP[(row + 16) * 128 + col4] =
                        *(const float4*)(Wi + (long long)(k0y + row + 16) * REC + n0y + col4);
                }
                for (int h = 0; h < 2; ++h) {
                    __syncthreads();
                    {   // stage xP [32 e][64 b] (transpose)
                        const int b = tid & 63, e4 = (tid >> 6) * 4;
                        const float4 v = *(const float4*)(x + ((long long)b * NSTEP + (t0 + h)) * EDIM + k0y + e4);
                        xP[(e4    ) * 64 + b] = v.x;
                        xP[(e4 + 1) * 64 + b] = v.y;
                        xP[(e4 + 2) * 64 + b] = v.z;
                        xP[(e4 + 3) * 64 + b] = v.w;
                    }
                    __syncthreads();
#pragma unroll 8
                    for (int kk = 0; kk < 32; ++kk) {
                        const float4 af = *(const float4*)&xP[kk * 64 + tr4];
                        const float4 bf = *(const float4*)&WiP[kk * 128 + tc4];
                        const float av[4] = {af.x, af.y, af.z, af.w};
#pragma unroll
                        for (int i = 0; i < 4; ++i) {
                            acc[h][i].x += av[i] * bf.x;
                            acc[h][i].y += av[i] * bf.y;
                            acc[h][i].z += av[i] * bf.z;
                            acc[h][i].w += av[i] * bf.w;
                        }
                    }
                }
            }
            // write Y tiles (bf16, sc1 write-through for cross-XCD visibility)
#pragma unroll
            for (int h = 0; h < 2; ++h)
#pragma unroll
                for (int i = 0; i < 4; ++i) {
                    const long long yrow = (long long)(t0 + h) * 64 + tr4 + i;
                    u16 o[4];
                    o[0] = __builtin_bit_cast(u16, (__bf16)acc[h][i].x);
                    o[1] = __builtin_bit_cast(u16, (__bf16)acc[h][i].y);
                    o[2] = __builtin_bit_cast(u16, (__bf16)acc[h][i].z);
                    o[3] = __builtin_bit_cast(u16, (__bf16)acc[h][i].w);
                    unsigned long long pk; __builtin_memcpy(&pk, o, 8);
                    cstore8u(&Ybf[yrow * REC + n0y + tc4], pk);
                }
        }
    }
    // ---- zero rT (3 comps, 786432 B = 98304 8-B chunks) ----
    {
        const int g = bid * 512 + tid;
        if (g < 98304) cstore8u(rTu + (long long)g * 4, 0ull);
    }
    ++gen; gbar(bar, bid, gen);

    // ================= one-time: stage + split Wr tile into LDS =============
    {
        for (int it = 0; it < 32; ++it) {
            const int row = it * 8 + wid;       // one row per wave
            const int col = lane;
            const float v = Wr[(long long)(kcbase + row) * REC + n0 + col];
            u16 s0, s1, s2; split3(v, s0, s1, s2);
            const int base = col * 264 + row;
            WrSu[base] = s0;
            WrSu[16896 + base] = s1;
            WrSu[33792 + base] = s2;
        }
        __syncthreads();
    }

    // ================= main recurrence ======================================
    for (int t = 0; t < NSTEP; ++t) {
        // ---- phase A: z partial via 6-pass split-bf16 MFMA ----
        f32x4 acc0 = {0,0,0,0}, acc1 = {0,0,0,0};
        const int sb = tid >> 3, sc = (tid & 7) * 8;   // staging: b, k-chunk
        for (int r = 0; r < 4; ++r) {
            __syncthreads();   // aS free (prev round consumed / barrier passed)
#pragma unroll
            for (int c = 0; c < 3; ++c) {   // stage aS round: 64b x 64k bf16
                const long long src = (long long)c * 131072 + (long long)sb * REC + kcbase + r * 64 + sc;
                unsigned long long v0 = cload8u(rTu + src);
                unsigned long long v1 = cload8u(rTu + src + 4);
                const int dst = c * 4608 + sb * 72 + sc;
                *(unsigned long long*)&aSu[dst] = v0;
                *(unsigned long long*)&aSu[dst + 4] = v1;
            }
            __syncthreads();
#pragma unroll
            for (int ks = 0; ks < 2; ++ks) {
                const int ka = ks * 32 + q * 8;            // aS k-local
                const int kb = r * 64 + ks * 32 + q * 8;   // WrS k-local
                const u16* ap = aSu + (Moff + l16) * 72 + ka;
                bf16x8 A0 = *(const bf16x8*)(ap);
                bf16x8 A1 = *(const bf16x8*)(ap + 4608);
                bf16x8 A2 = *(const bf16x8*)(ap + 9216);
                const u16* bp0 = WrSu + (Npair * 32 + l16) * 264 + kb;
                bf16x8 B00 = *(const bf16x8*)(bp0);
                bf16x8 B01 = *(const bf16x8*)(bp0 + 16896);
                bf16x8 B02 = *(const bf16x8*)(bp0 + 33792);
                acc0 = mfma16(A0, B00, acc0);
                acc0 = mfma16(A0, B01, acc0);
                acc0 = mfma16(A1, B00, acc0);
                acc0 = mfma16(A0, B02, acc0);
                acc0 = mfma16(A1, B01, acc0);
                acc0 = mfma16(A2, B00, acc0);
                const u16* bp1 = bp0 + 16 * 264;
                bf16x8 B10 = *(const bf16x8*)(bp1);
                bf16x8 B11 = *(const bf16x8*)(bp1 + 16896);
                bf16x8 B12 = *(const bf16x8*)(bp1 + 33792);
                acc1 = mfma16(A0, B10, acc1);
                acc1 = mfma16(A0, B11, acc1);
                acc1 = mfma16(A1, B10, acc1);
                acc1 = mfma16(A0, B12, acc1);
                acc1 = mfma16(A1, B11, acc1);
                acc1 = mfma16(A2, B10, acc1);
            }
        }
        {   // store zpart: D[row=q*4+i][col=l16] per tile (m89 C/D layout)
            const int colA = n0 + Npair * 32 + l16;
#pragma unroll
            for (int i = 0; i < 4; ++i) {
                const long long rowz = (long long)(kc * 64 + Moff + q * 4 + i) * REC;
                cstore4(zpart + rowz + colA,      ((float*)&acc0)[i]);
                cstore4(zpart + rowz + colA + 16, ((float*)&acc1)[i]);
            }
        }
        ++gen; gbar(bar, bid, gen);   // partials visible

        // ---- phase B: blocks 0..63, one batch row each ----
        if (bid < NB) {
            const int b = bid;
            const int j0 = tid * 4;
            float zs[4] = {0,0,0,0};
#pragma unroll
            for (int k2 = 0; k2 < KC; ++k2) {
                const long long base = ((long long)(k2 * 64) + b) * REC + j0;
                float2 u0 = cload8f(zpart + base);
                float2 u1 = cload8f(zpart + base + 2);
                zs[0] += u0.x; zs[1] += u0.y; zs[2] += u1.x; zs[3] += u1.y;
            }
            {
                uint4 kv; unsigned u;
                u = __float_as_uint(zs[0]); kv.x = (u & 0x80000000u) ? ~u : (u | 0x80000000u);
                u = __float_as_uint(zs[1]); kv.y = (u & 0x80000000u) ? ~u : (u | 0x80000000u);
                u = __float_as_uint(zs[2]); kv.z = (u & 0x80000000u) ? ~u : (u | 0x80000000u);
                u = __float_as_uint(zs[3]); kv.w = (u & 0x80000000u) ? ~u : (u | 0x80000000u);
                *(uint4*)&kS[j0] = kv;
            }
            __syncthreads();
            unsigned prefix = 0, remaining = KSEL;
            for (int byte = 3; byte >= 0; --byte) {
                if (tid < 256) hist[tid] = 0u;
                __syncthreads();
                const int shift = byte * 8;
                const unsigned pmask = (byte == 3) ? 0u : (0xFFFFFFFFu << (shift + 8));
#pragma unroll
                for (int s = 0; s < 4; ++s) {
                    const unsigned key = kS[j0 + s];
                    if ((key & pmask) == prefix)
                        atomicAdd(&hist[(key >> shift) & 255u], 1u);
                }
                __syncthreads();
                if (tid < 64) {
                    const unsigned h0 = hist[tid * 4 + 0];
                    const unsigned h1 = hist[tid * 4 + 1];
                    const unsigned h2 = hist[tid * 4 + 2];
                    const unsigned h3 = hist[tid * 4 + 3];
                    const unsigned tot = h0 + h1 + h2 + h3;
                    unsigned suf = tot;
#pragma unroll
                    for (int st = 1; st < 64; st <<= 1) {
                        unsigned o = __shfl_down(suf, (unsigned)st);
                        if (tid + st >= 64) o = 0u;
                        suf += o;
                    }
                    unsigned S[5];
                    S[0] = suf; S[1] = suf - h0; S[2] = suf - h0 - h1;
                    S[3] = suf - h0 - h1 - h2; S[4] = suf - tot;
#pragma unroll
                    for (int qq = 0; qq < 4; ++qq) {
                        if (S[qq] >= remaining && S[qq + 1] < remaining) {
                            s_byte = (unsigned)(tid * 4 + qq);
                            s_newrem = remaining - S[qq + 1];
                        }
                    }
                }
                __syncthreads();
                prefix |= (s_byte << shift);
                remaining = s_newrem;
                __syncthreads();
            }
            const unsigned T = prefix;
            const unsigned need = remaining;
            const unsigned cnteq = hist[T & 255u];
            if (need == cnteq) {
#pragma unroll
                for (int s = 0; s < 4; ++s)
                    selS[j0 + s] = (kS[j0 + s] >= T) ? 1 : 0;
                __syncthreads();
            } else {
                int c = 0; unsigned char eqv[4];
#pragma unroll
                for (int s = 0; s < 4; ++s) { eqv[s] = (kS[j0 + s] == T) ? 1 : 0; c += eqv[s]; }
                scn[tid] = (unsigned)c; __syncthreads();
                for (int st = 1; st < 512; st <<= 1) {
                    unsigned v2 = (tid >= st) ? scn[tid - st] : 0u;
                    __syncthreads();
                    scn[tid] += v2;
                    __syncthreads();
                }
                unsigned p = scn[tid] - (unsigned)c;
#pragma unroll
                for (int s = 0; s < 4; ++s) {
                    unsigned char sel;
                    if (eqv[s]) { sel = (p < need) ? 1 : 0; ++p; }
                    else        { sel = (kS[j0 + s] > T) ? 1 : 0; }
                    selS[j0 + s] = sel;
                }
                __syncthreads();
            }
            // r_new = tanh(y + masked z), row-normalize
            float rn[4]; float ss = 0.f;
            {
                const ushort4 yv = *(const ushort4*)&Ybf[((long long)t * 64 + b) * REC + j0];
                const u16 ya[4] = {yv.x, yv.y, yv.z, yv.w};
#pragma unroll
                for (int s = 0; s < 4; ++s) {
                    const float y = __uint_as_float(((unsigned)ya[s]) << 16);
                    const float v = y + (selS[j0 + s] ? zs[s] : 0.f);
                    const float th = tanhf(v);
                    rn[s] = th; ss += th * th;
                }
            }
#pragma unroll
            for (int off = 32; off > 0; off >>= 1)
                ss += __shfl_down(ss, (unsigned)off);
            if ((tid & 63) == 0) red[tid >> 6] = ss;
            __syncthreads();
            if (tid == 0) {
                float a = 0.f;
#pragma unroll
                for (int i = 0; i < 8; ++i) a += red[i];
                s_norm = sqrtf(a) + 1e-6f;
            }
            __syncthreads();
            const float inv = 1.0f / s_norm;
            u16 o0[4], o1[4], o2[4];
#pragma unroll
            for (int s = 0; s < 4; ++s) {
                const float v = rn[s] * inv;
                rn[s] = v;
                split3(v, o0[s], o1[s], o2[s]);
            }
            unsigned long long p0, p1, p2;
            __builtin_memcpy(&p0, o0, 8); __builtin_memcpy(&p1, o1, 8); __builtin_memcpy(&p2, o2, 8);
            const long long rbase = (long long)b * REC + j0;
            cstore8u(rTu + rbase, p0);
            cstore8u(rTu + 131072 + rbase, p1);
            cstore8u(rTu + 262144 + rbase, p2);
            if (t == NSTEP - 1)
                *(float4*)&out[rbase] = make_float4(rn[0], rn[1], rn[2], rn[3]);
        }
        ++gen; gbar(bar, bid, gen);   // r ready for next step
    }
}

// ---------------------------------------------------------------------------
extern "C" void kernel_launch(void* const* d_in, const int* in_sizes, int n_in,
                              void* d_out, int out_size, void* d_ws, size_t ws_size,
                              hipStream_t stream)
{
    const float* x   = (const float*)d_in[0];   // [64][512][512]
    const float* Win = (const float*)d_in[1];   // [512][2048]
    const float* Wr  = (const float*)d_in[2];   // [2048][2048]
    float* out = (float*)d_out;                 // [64][2048]

    char* ws = (char*)d_ws;
    unsigned* bar = (unsigned*)ws;                         // 8 KB
    float* zpart  = (float*)(ws + 8192);                   // 4 MB  [8*64][2048] f32
    u16*   rTu    = (u16*)(ws + 8192 + 4194304);           // 768 KB: 3 comps [64][2048] bf16
    u16*   Ybf    = (u16*)(ws + 8192 + 4194304 + 786432);  // 128 MB [512*64][2048] bf16

    static int smem_set = 0;
    if (!smem_set) {
        hipFuncSetAttribute((const void*)rnn_persistent,
                            hipFuncAttributeMaxDynamicSharedMemorySize, 129024);
        smem_set = 1;
    }
    hipMemsetAsync(bar, 0, 8192, stream);
    rnn_persistent<<<256, 512, 129024, stream>>>(x, Win, Wr, out, rTu, zpart, Ybf, bar);
}

// Round 5
// 11103.008 us; speedup vs baseline: 3.6670x; 1.0813x over previous
//
#include <hip/hip_runtime.h>

#define NSTEP 512
#define EDIM  512
#define REC   2048
#define NB    64
#define KSEL  819
#define NC    32      // col chunks of 64
#define KC    8       // K chunks of 256
#define ZCH   256     // K per block
#define AP    264     // padded k-stride (u16) for LDS tiles
#define CSTR  16896   // 64*AP: component stride inside LDS tiles

typedef unsigned short u16;
typedef __bf16 bf16x8 __attribute__((ext_vector_type(8)));
typedef float  f32x4  __attribute__((ext_vector_type(4)));
typedef unsigned long long ull;

static __device__ __forceinline__ f32x4 mfma16(bf16x8 a, bf16x8 b, f32x4 c) {
    return __builtin_amdgcn_mfma_f32_16x16x32_bf16(a, b, c, 0, 0, 0);
}

// fp32 -> 2 bf16 components (hi, lo): ~17 mantissa bits
static __device__ __forceinline__ void split2(float v, u16& c0, u16& c1) {
    __bf16 b0 = (__bf16)v;
    __bf16 b1 = (__bf16)(v - (float)b0);
    c0 = __builtin_bit_cast(u16, b0);
    c1 = __builtin_bit_cast(u16, b1);
}

// ---- agent-scope (sc1) coherent access helpers (proven r3/r4) ----
static __device__ __forceinline__ void cstore4(float* p, float v) {
    __hip_atomic_store((unsigned*)p, __float_as_uint(v), __ATOMIC_RELAXED, __HIP_MEMORY_SCOPE_AGENT);
}
static __device__ __forceinline__ void cstore8u(void* p, ull v) {
    __hip_atomic_store((ull*)p, v, __ATOMIC_RELAXED, __HIP_MEMORY_SCOPE_AGENT);
}
static __device__ __forceinline__ ull cload8u(const void* p) {
    return __hip_atomic_load((const ull*)p, __ATOMIC_RELAXED, __HIP_MEMORY_SCOPE_AGENT);
}
static __device__ __forceinline__ float2 cload8f(const float* p) {
    ull u = cload8u(p);
    float2 v; __builtin_memcpy(&v, &u, 8);
    return v;
}

// ---- two-level grid barrier (proven r3/r4) ----
__device__ __forceinline__ void gbar(unsigned* bar, int bid, unsigned gen)
{
    __syncthreads();
    if (threadIdx.x == 0) {
        const int g = bid >> 4;
        unsigned v = __hip_atomic_fetch_add(&bar[g * 32], 1u,
                        __ATOMIC_RELAXED, __HIP_MEMORY_SCOPE_AGENT);
        if (v + 1u == gen * 16u)
            __hip_atomic_fetch_add(&bar[1024], 1u,
                        __ATOMIC_RELAXED, __HIP_MEMORY_SCOPE_AGENT);
        while (__hip_atomic_load(&bar[1024], __ATOMIC_RELAXED,
                        __HIP_MEMORY_SCOPE_AGENT) < gen * 16u)
            __builtin_amdgcn_s_sleep(1);
        __asm__ volatile("" ::: "memory");
    }
    __syncthreads();
}

// ---------------------------------------------------------------------------
// Persistent kernel: 256 blocks x 512 threads.
// LDS (135168 B dynamic):
//   WrSu: 2 x [64 n][264 k] bf16 @0      (67584 B)  transposed, pad-264
//   aSu : 2 x [64 b][264 k] bf16 @67584  (67584 B)  full K=256 slice
//   update scratch aliases aSu; Y-precompute WiP/xP alias WrSu.
// ---------------------------------------------------------------------------
__global__ __launch_bounds__(512, 1)
void rnn_persistent(const float* __restrict__ x, const float* __restrict__ Wi,
                    const float* __restrict__ Wr, float* __restrict__ out,
                    u16* __restrict__ rTu, float* __restrict__ zpart,
                    u16* __restrict__ Ybf, unsigned* __restrict__ bar)
{
    extern __shared__ __align__(16) char smem[];
    u16* WrSu = (u16*)smem;                         // + c*CSTR
    u16* aSu  = (u16*)(smem + 2 * CSTR * 2);        // byte 67584, + c*CSTR
    // Y-precompute views (alias WrS region)
    float* WiP = (float*)smem;                      // [32][128] 16 KB
    float* xP  = (float*)(smem + 16384);            // [32][64]   8 KB
    // update-phase views (alias aS region)
    unsigned*      kS   = (unsigned*)(smem + 67584);          // [2048] 8 KB
    unsigned char* selS = (unsigned char*)(smem + 67584 + 8192);
    unsigned*      hist = (unsigned*)(smem + 67584 + 10240);
    unsigned*      scn  = (unsigned*)(smem + 67584 + 11264);
    __shared__ unsigned s_byte, s_newrem;
    __shared__ float red[8];
    __shared__ float s_norm;

    const int bid = blockIdx.x;
    const int tid = threadIdx.x;
    const int nc = bid & 31, kc = bid >> 5;
    const int n0 = nc * 64, kcbase = kc * ZCH;
    const int wid = tid >> 6, lane = tid & 63;
    const int q = lane >> 4, l16 = lane & 15;
    const int Moff = (wid & 3) * 16, Npair = wid >> 2;
    unsigned gen = 0;

    // ================= Y precompute (unchanged from r4, proven) =============
    {
        const int t0 = bid * 2;
        const int tr4 = (tid >> 5) * 4;
        const int tc4 = (tid & 31) * 4;
        for (int nc2 = 0; nc2 < 16; ++nc2) {
            const int n0y = nc2 * 128;
            f32x4 acc[2][4];
#pragma unroll
            for (int h = 0; h < 2; ++h)
#pragma unroll
                for (int i = 0; i < 4; ++i) acc[h][i] = (f32x4){0,0,0,0};
            for (int kr = 0; kr < 16; ++kr) {
                const int k0y = kr * 32;
                __syncthreads();
                {
                    const int col4 = (tid & 31) * 4, row = tid >> 5;
                    *(float4*)&WiP[row * 128 + col4] =
                        *(const float4*)(Wi + (long long)(k0y + row) * REC + n0y + col4);
                    *(float4*)&WiP[(row + 16) * 128 + col4] =
                        *(const float4*)(Wi + (long long)(k0y + row + 16) * REC + n0y + col4);
                }
                for (int h = 0; h < 2; ++h) {
                    __syncthreads();
                    {
                        const int b = tid & 63, e4 = (tid >> 6) * 4;
                        const float4 v = *(const float4*)(x + ((long long)b * NSTEP + (t0 + h)) * EDIM + k0y + e4);
                        xP[(e4    ) * 64 + b] = v.x;
                        xP[(e4 + 1) * 64 + b] = v.y;
                        xP[(e4 + 2) * 64 + b] = v.z;
                        xP[(e4 + 3) * 64 + b] = v.w;
                    }
                    __syncthreads();
#pragma unroll 8
                    for (int kk = 0; kk < 32; ++kk) {
                        const float4 af = *(const float4*)&xP[kk * 64 + tr4];
                        const float4 bf = *(const float4*)&WiP[kk * 128 + tc4];
                        const float av[4] = {af.x, af.y, af.z, af.w};
#pragma unroll
                        for (int i = 0; i < 4; ++i) {
                            acc[h][i].x += av[i] * bf.x;
                            acc[h][i].y += av[i] * bf.y;
                            acc[h][i].z += av[i] * bf.z;
                            acc[h][i].w += av[i] * bf.w;
                        }
                    }
                }
            }
#pragma unroll
            for (int h = 0; h < 2; ++h)
#pragma unroll
                for (int i = 0; i < 4; ++i) {
                    const long long yrow = (long long)(t0 + h) * 64 + tr4 + i;
                    u16 o[4];
                    o[0] = __builtin_bit_cast(u16, (__bf16)acc[h][i].x);
                    o[1] = __builtin_bit_cast(u16, (__bf16)acc[h][i].y);
                    o[2] = __builtin_bit_cast(u16, (__bf16)acc[h][i].z);
                    o[3] = __builtin_bit_cast(u16, (__bf16)acc[h][i].w);
                    ull pk; __builtin_memcpy(&pk, o, 8);
                    cstore8u(&Ybf[yrow * REC + n0y + tc4], pk);
                }
        }
    }
    // ---- zero rT (2 comps x 131072 u16 = 65536 8-B chunks) ----
    {
        const int g = bid * 512 + tid;
        if (g < 65536) cstore8u(rTu + (long long)g * 4, 0ull);
    }
    ++gen; gbar(bar, bid, gen);

    // ================= one-time: stage + split Wr tile into LDS =============
    {
        for (int it = 0; it < 32; ++it) {
            const int row = it * 8 + wid;       // k index within slice
            const int col = lane;               // n index
            const float v = Wr[(long long)(kcbase + row) * REC + n0 + col];
            u16 s0, s1; split2(v, s0, s1);
            const int base = col * AP + row;
            WrSu[base] = s0;
            WrSu[CSTR + base] = s1;
        }
        __syncthreads();
    }

    // ================= main recurrence ======================================
    const int hw = tid >> 5, hl = tid & 31;     // half-wave id / lane
    for (int t = 0; t < NSTEP; ++t) {
        // ---- stage full aS slice: 2 comps x 64 rows x 256 u16, one round ----
        {
            ull va[8], vb[8];
#pragma unroll
            for (int i = 0; i < 8; ++i) {
                const int c = i >> 2;
                const int b = (i & 3) * 16 + hw;
                const u16* src = rTu + c * 131072 + b * REC + kcbase + hl * 8;
                va[i] = cload8u(src);
                vb[i] = cload8u(src + 4);
            }
#pragma unroll
            for (int i = 0; i < 8; ++i) {
                const int c = i >> 2;
                const int b = (i & 3) * 16 + hw;
                u16* dst = aSu + c * CSTR + b * AP + hl * 8;
                *(ull*)dst = va[i];
                *(ull*)(dst + 4) = vb[i];
            }
            __syncthreads();
        }
        // ---- z partial: 3-pass split-bf16 MFMA, K=256 in LDS ----
        f32x4 acc0 = {0,0,0,0}, acc1 = {0,0,0,0};
#pragma unroll
        for (int ks = 0; ks < 8; ++ks) {
            const int kk = ks * 32 + q * 8;
            const u16* ap = aSu + (Moff + l16) * AP + kk;
            bf16x8 A0 = *(const bf16x8*)(ap);
            bf16x8 A1 = *(const bf16x8*)(ap + CSTR);
            const u16* bp0 = WrSu + (Npair * 32 + l16) * AP + kk;
            bf16x8 B00 = *(const bf16x8*)(bp0);
            bf16x8 B01 = *(const bf16x8*)(bp0 + CSTR);
            const u16* bp1 = bp0 + 16 * AP;
            bf16x8 B10 = *(const bf16x8*)(bp1);
            bf16x8 B11 = *(const bf16x8*)(bp1 + CSTR);
            acc0 = mfma16(A0, B00, acc0);
            acc1 = mfma16(A0, B10, acc1);
            acc0 = mfma16(A0, B01, acc0);
            acc1 = mfma16(A0, B11, acc1);
            acc0 = mfma16(A1, B00, acc0);
            acc1 = mfma16(A1, B10, acc1);
        }
        {   // store zpart: D[row=q*4+i][col=l16] (m89 C/D layout, proven r4)
            const int colA = n0 + Npair * 32 + l16;
#pragma unroll
            for (int i = 0; i < 4; ++i) {
                const long long rowz = (long long)(kc * 64 + Moff + q * 4 + i) * REC;
                cstore4(zpart + rowz + colA,      ((float*)&acc0)[i]);
                cstore4(zpart + rowz + colA + 16, ((float*)&acc1)[i]);
            }
        }
        ++gen; gbar(bar, bid, gen);   // partials visible

        // ---- phase B: 64 spread blocks (bid%4==0), one batch row each ----
        if ((bid & 3) == 0) {
            const int b = bid >> 2;
            const int j0 = tid * 4;
            float zs[4] = {0,0,0,0};
#pragma unroll
            for (int k2 = 0; k2 < KC; ++k2) {
                const long long base = ((long long)(k2 * 64) + b) * REC + j0;
                float2 u0 = cload8f(zpart + base);
                float2 u1 = cload8f(zpart + base + 2);
                zs[0] += u0.x; zs[1] += u0.y; zs[2] += u1.x; zs[3] += u1.y;
            }
            {
                uint4 kv; unsigned u;
                u = __float_as_uint(zs[0]); kv.x = (u & 0x80000000u) ? ~u : (u | 0x80000000u);
                u = __float_as_uint(zs[1]); kv.y = (u & 0x80000000u) ? ~u : (u | 0x80000000u);
                u = __float_as_uint(zs[2]); kv.z = (u & 0x80000000u) ? ~u : (u | 0x80000000u);
                u = __float_as_uint(zs[3]); kv.w = (u & 0x80000000u) ? ~u : (u | 0x80000000u);
                *(uint4*)&kS[j0] = kv;
            }
            __syncthreads();
            unsigned prefix = 0, remaining = KSEL;
            for (int byte = 3; byte >= 0; --byte) {
                if (tid < 256) hist[tid] = 0u;
                __syncthreads();
                const int shift = byte * 8;
                const unsigned pmask = (byte == 3) ? 0u : (0xFFFFFFFFu << (shift + 8));
#pragma unroll
                for (int s = 0; s < 4; ++s) {
                    const unsigned key = kS[j0 + s];
                    if ((key & pmask) == prefix)
                        atomicAdd(&hist[(key >> shift) & 255u], 1u);
                }
                __syncthreads();
                if (tid < 64) {
                    const unsigned h0 = hist[tid * 4 + 0];
                    const unsigned h1 = hist[tid * 4 + 1];
                    const unsigned h2 = hist[tid * 4 + 2];
                    const unsigned h3 = hist[tid * 4 + 3];
                    const unsigned tot = h0 + h1 + h2 + h3;
                    unsigned suf = tot;
#pragma unroll
                    for (int st = 1; st < 64; st <<= 1) {
                        unsigned o = __shfl_down(suf, (unsigned)st);
                        if (tid + st >= 64) o = 0u;
                        suf += o;
                    }
                    unsigned S[5];
                    S[0] = suf; S[1] = suf - h0; S[2] = suf - h0 - h1;
                    S[3] = suf - h0 - h1 - h2; S[4] = suf - tot;
#pragma unroll
                    for (int qq = 0; qq < 4; ++qq) {
                        if (S[qq] >= remaining && S[qq + 1] < remaining) {
                            s_byte = (unsigned)(tid * 4 + qq);
                            s_newrem = remaining - S[qq + 1];
                        }
                    }
                }
                __syncthreads();
                prefix |= (s_byte << shift);
                remaining = s_newrem;
                __syncthreads();
            }
            const unsigned T = prefix;
            const unsigned need = remaining;
            const unsigned cnteq = hist[T & 255u];
            if (need == cnteq) {
#pragma unroll
                for (int s = 0; s < 4; ++s)
                    selS[j0 + s] = (kS[j0 + s] >= T) ? 1 : 0;
                __syncthreads();
            } else {
                int c = 0; unsigned char eqv[4];
#pragma unroll
                for (int s = 0; s < 4; ++s) { eqv[s] = (kS[j0 + s] == T) ? 1 : 0; c += eqv[s]; }
                scn[tid] = (unsigned)c; __syncthreads();
                for (int st = 1; st < 512; st <<= 1) {
                    unsigned v2 = (tid >= st) ? scn[tid - st] : 0u;
                    __syncthreads();
                    scn[tid] += v2;
                    __syncthreads();
                }
                unsigned p = scn[tid] - (unsigned)c;
#pragma unroll
                for (int s = 0; s < 4; ++s) {
                    unsigned char sel;
                    if (eqv[s]) { sel = (p < need) ? 1 : 0; ++p; }
                    else        { sel = (kS[j0 + s] > T) ? 1 : 0; }
                    selS[j0 + s] = sel;
                }
                __syncthreads();
            }
            // r_new = tanh(y + masked z), row-normalize
            float rn[4]; float ss = 0.f;
            {
                const ushort4 yv = *(const ushort4*)&Ybf[((long long)t * 64 + b) * REC + j0];
                const u16 ya[4] = {yv.x, yv.y, yv.z, yv.w};
#pragma unroll
                for (int s = 0; s < 4; ++s) {
                    const float y = __uint_as_float(((unsigned)ya[s]) << 16);
                    const float v = y + (selS[j0 + s] ? zs[s] : 0.f);
                    const float th = tanhf(v);
                    rn[s] = th; ss += th * th;
                }
            }
#pragma unroll
            for (int off = 32; off > 0; off >>= 1)
                ss += __shfl_down(ss, (unsigned)off);
            if ((tid & 63) == 0) red[tid >> 6] = ss;
            __syncthreads();
            if (tid == 0) {
                float a = 0.f;
#pragma unroll
                for (int i = 0; i < 8; ++i) a += red[i];
                s_norm = sqrtf(a) + 1e-6f;
            }
            __syncthreads();
            const float inv = 1.0f / s_norm;
            u16 o0[4], o1[4];
#pragma unroll
            for (int s = 0; s < 4; ++s) {
                const float v = rn[s] * inv;
                rn[s] = v;
                split2(v, o0[s], o1[s]);
            }
            ull p0, p1;
            __builtin_memcpy(&p0, o0, 8); __builtin_memcpy(&p1, o1, 8);
            const long long rbase = (long long)b * REC + j0;
            cstore8u(rTu + rbase, p0);
            cstore8u(rTu + 131072 + rbase, p1);
            if (t == NSTEP - 1)
                *(float4*)&out[rbase] = make_float4(rn[0], rn[1], rn[2], rn[3]);
        }
        ++gen; gbar(bar, bid, gen);   // r ready for next step
    }
}

// ---------------------------------------------------------------------------
extern "C" void kernel_launch(void* const* d_in, const int* in_sizes, int n_in,
                              void* d_out, int out_size, void* d_ws, size_t ws_size,
                              hipStream_t stream)
{
    const float* x   = (const float*)d_in[0];   // [64][512][512]
    const float* Win = (const float*)d_in[1];   // [512][2048]
    const float* Wr  = (const float*)d_in[2];   // [2048][2048]
    float* out = (float*)d_out;                 // [64][2048]

    char* ws = (char*)d_ws;
    unsigned* bar = (unsigned*)ws;                         // 8 KB
    float* zpart  = (float*)(ws + 8192);                   // 4 MB [8*64][2048] f32
    u16*   rTu    = (u16*)(ws + 8192 + 4194304);           // 512 KB: 2 comps [64][2048] bf16
    u16*   Ybf    = (u16*)(ws + 8192 + 4194304 + 524288);  // 128 MB [512*64][2048] bf16

    static int smem_set = 0;
    if (!smem_set) {
        hipFuncSetAttribute((const void*)rnn_persistent,
                            hipFuncAttributeMaxDynamicSharedMemorySize, 135168);
        smem_set = 1;
    }
    hipMemsetAsync(bar, 0, 8192, stream);
    rnn_persistent<<<256, 512, 135168, stream>>>(x, Win, Wr, out, rTu, zpart, Ybf, bar);
}